// Round 9
// baseline (291.173 us; speedup 1.0000x reference)
//
#include <hip/hip_runtime.h>
#include <hip/hip_fp16.h>
#include <math.h>

#define HH 256
#define WW 256
#define NB 4
#define NN 256
#define NSTEPS 50
#define STEPSZ 0.1f
#define ALPHA 0.01f
#define BETA 0.005f
#define DMAX 15.0f
#define CTILE 4
#define CH (CTILE + 1 + 12)   // 17 staged rows: need CTILE+1 vertical results

struct Flt { float g[13]; float dg[13]; };

// ---- cross-block gate helpers (agent scope; same pattern as the validated
// last-block reduction). publish: all stores -> fence -> sync -> +1.
__device__ __forceinline__ void publish(unsigned* gate) {
    __threadfence();                       // agent-scope release of my stores
    __syncthreads();                       // all threads' fences complete
    if (threadIdx.x == 0)
        __hip_atomic_fetch_add(gate, 1u, __ATOMIC_RELEASE,
                               __HIP_MEMORY_SCOPE_AGENT);
}
template <int SLP>
__device__ __forceinline__ void waitgate(unsigned* gate, unsigned target) {
    if (threadIdx.x == 0) {
        while (__hip_atomic_load(gate, __ATOMIC_ACQUIRE,
                                 __HIP_MEMORY_SCOPE_AGENT) < target)
            __builtin_amdgcn_s_sleep(SLP);
    }
    __syncthreads();
    __threadfence();                       // acquire side for normal loads
}

// One-cache-line bilinear sample from the pre-gathered record image.
__device__ __forceinline__ void sampleR(const uint4* __restrict__ rec,
                                        float py_, float px_,
                                        float& fy, float& fx, float& fw) {
    float yc = fminf(fmaxf(py_, 0.f), 254.999f);
    float xc = fminf(fmaxf(px_, 0.f), 254.999f);
    int y0 = (int)yc, x0 = (int)xc;
    float ty = yc - (float)y0, tx = xc - (float)x0;
    const uint4* p = rec + (size_t)((y0 << 8) + x0) * 2;
    union { uint4 u; __half h[8]; } lo;
    union { uint2 u; __half h[4]; } hi;
    lo.u = p[0];
    hi.u = *(const uint2*)(p + 1);
    float w00 = (1.f - ty) * (1.f - tx), w01 = (1.f - ty) * tx;
    float w10 = ty * (1.f - tx),         w11 = ty * tx;
    fy = __half2float(lo.h[0]) * w00 + __half2float(lo.h[3]) * w01 +
         __half2float(lo.h[6]) * w10 + __half2float(hi.h[1]) * w11;
    fx = __half2float(lo.h[1]) * w00 + __half2float(lo.h[4]) * w01 +
         __half2float(lo.h[7]) * w10 + __half2float(hi.h[2]) * w11;
    fw = __half2float(lo.h[2]) * w00 + __half2float(lo.h[5]) * w01 +
         __half2float(hi.h[0]) * w10 + __half2float(hi.h[3]) * w11;
}

// Barrier that waits ONLY on LDS ops (lgkmcnt(0)); outstanding global gathers
// stay in flight across it. imm 0xC07F: vmcnt=63, expcnt=7, lgkmcnt=0.
__device__ __forceinline__ void barrier_lds_only() {
    __asm__ volatile("" ::: "memory");
    __builtin_amdgcn_s_waitcnt(0xC07F);
    __builtin_amdgcn_s_barrier();
    __asm__ volatile("" ::: "memory");
}

// ONE persistent kernel: conv -> gate -> snake (blocks 0-3) -> gate -> render.
// Grid = 256 blocks x 256 threads: co-resident on 256 CUs (worst case 2/CU
// still fits: 8 waves, 2x34KB LDS), so spin-gates cannot deadlock.
__global__ void fused_kernel(const float* __restrict__ pd,
                             const float* __restrict__ node_pos,
                             const float* __restrict__ widths,
                             uint4* __restrict__ rec,
                             float4* __restrict__ nodes,
                             float* __restrict__ partial,
                             unsigned* __restrict__ gates,
                             float* __restrict__ out, Flt flt) {
    __shared__ union SM {
        struct { float srow[CH][WW + 16]; float vres[CTILE + 1][WW + 2][3]; } c;
        struct { float4 buf[2][NN]; } s;
        struct { float4 list[NN]; } r;
    } sm;
    __shared__ int wbase[4];
    __shared__ int total;
    __shared__ float wsum[4];
    __shared__ int lastflag;

    int g = blockIdx.x;
    int x = threadIdx.x;

    // ---------------- Stage A: conv (all 256 blocks; 4 rows each) ----------
    {
        int b = g >> 6;
        int t = g & 63;
        int y0 = t * CTILE;
        for (int r = 0; r < CH; ++r) {
            int yy = y0 - 6 + r;
            float v = (yy >= 0 && yy < HH) ? pd[((size_t)b * HH + yy) * WW + x]
                                           : 0.f;
            sm.c.srow[r][6 + x] = v;
            if (x < 6) { sm.c.srow[r][x] = 0.f; sm.c.srow[r][WW + 6 + x] = 0.f; }
        }
        __syncthreads();
        float4 h[CH];
#pragma unroll
        for (int r = 0; r < CH; ++r) {
            float sg = 0.f, sdg = 0.f, sga = 0.f, sdga = 0.f;
#pragma unroll
            for (int j = 0; j < 13; ++j) {
                float v = sm.c.srow[r][x + j];
                float a = fabsf(v);
                sg   += flt.g[j]  * v;
                sdg  += flt.dg[j] * v;
                sga  += flt.g[j]  * a;
                sdga += flt.dg[j] * a;
            }
            h[r] = make_float4(sg, sdg, sga, sdga);
        }
#pragma unroll
        for (int rr = 0; rr <= CTILE; ++rr) {
            float g0 = 0.f, g1 = 0.f, w0 = 0.f, w1 = 0.f;
#pragma unroll
            for (int i2 = 0; i2 < 13; ++i2) {
                float4 v = h[rr + i2];
                g0 += flt.dg[i2] * v.x;   // fy: dg over y of (g over x)
                g1 += flt.g[i2]  * v.y;   // fx: g over y of (dg over x)
                w0 += flt.dg[i2] * v.z;
                w1 += flt.g[i2]  * v.w;
            }
            sm.c.vres[rr][x][0] = 10.f * g0;
            sm.c.vres[rr][x][1] = 10.f * g1;
            sm.c.vres[rr][x][2] = 10.f * (w0 + w1);
        }
        __syncthreads();
#pragma unroll
        for (int rr = 0; rr < CTILE; ++rr) {
            const float* c00 = sm.c.vres[rr][x];
            const float* c01 = sm.c.vres[rr][x + 1];   // x=255: garbage col,
            const float* c10 = sm.c.vres[rr + 1][x];   // record never sampled
            const float* c11 = sm.c.vres[rr + 1][x + 1];
            union { uint4 u; __half hh[8]; } lo;
            union { uint2 u; __half hh[4]; } hi;
            lo.hh[0] = __float2half(c00[0]); lo.hh[1] = __float2half(c00[1]);
            lo.hh[2] = __float2half(c00[2]);
            lo.hh[3] = __float2half(c01[0]); lo.hh[4] = __float2half(c01[1]);
            lo.hh[5] = __float2half(c01[2]);
            lo.hh[6] = __float2half(c10[0]); lo.hh[7] = __float2half(c10[1]);
            hi.hh[0] = __float2half(c10[2]);
            hi.hh[1] = __float2half(c11[0]); hi.hh[2] = __float2half(c11[1]);
            hi.hh[3] = __float2half(c11[2]);
            size_t ridx = ((size_t)b * HH + y0 + rr) * WW + x;
            rec[ridx * 2] = lo.u;
            *((uint2*)(rec + ridx * 2 + 1)) = hi.u;
        }
    }
    publish(&gates[0]);

    // ---------------- Stage B: snake (blocks 0-3 only) ---------------------
    if (g < NB) {
        waitgate<2>(&gates[0], 256);
        int b = g;
        int i = x;
        const uint4* img = rec + (size_t)b * HH * WW * 2;
        const float2* np2 = (const float2*)(node_pos + (size_t)b * NN * 2);
        float2 pc = np2[i];
        float wc = widths[(size_t)b * NN + i];
        sm.s.buf[0][i] = make_float4(pc.x, pc.y, wc, 0.f);
        int im1 = (i > 0) ? i - 1 : 0;
        int im2 = (i > 1) ? i - 2 : 0;
        int ip1 = (i < NN - 1) ? i + 1 : NN - 1;
        int ip2 = (i < NN - 2) ? i + 2 : NN - 1;
        float fy, fx, fw;
        sampleR(img, pc.x, pc.y, fy, fx, fw);
        __syncthreads();
        int cur = 0;
        for (int s = 0; s < NSTEPS; ++s) {
            int nxt = cur ^ 1;
            float4 m2 = sm.s.buf[cur][im2], m1 = sm.s.buf[cur][im1];
            float4 p1 = sm.s.buf[cur][ip1], p2 = sm.s.buf[cur][ip2];
            float d2y = m1.x - 2.f * pc.x + p1.x;
            float d2x = m1.y - 2.f * pc.y + p1.y;
            float d2my = m2.x - 2.f * m1.x + pc.x;
            float d2mx = m2.y - 2.f * m1.y + pc.y;
            float d2py = pc.x - 2.f * p1.x + p2.x;
            float d2px = pc.y - 2.f * p1.y + p2.y;
            if (i == 0)      { d2my = d2y; d2mx = d2x; }
            if (i == NN - 1) { d2py = d2y; d2px = d2x; }
            float d4y = d2my - 2.f * d2y + d2py;
            float d4x = d2mx - 2.f * d2x + d2px;
            pc.x = fminf(fmaxf(pc.x + STEPSZ * (ALPHA * d2y - BETA * d4y + fy),
                               0.f), (float)(HH - 1));
            pc.y = fminf(fmaxf(pc.y + STEPSZ * (ALPHA * d2x - BETA * d4x + fx),
                               0.f), (float)(WW - 1));
            *((float2*)&sm.s.buf[nxt][i]) = pc;
            float nfy, nfx, nfw;
            sampleR(img, pc.x, pc.y, nfy, nfx, nfw);  // in flight past barrier
            float d2w = m1.z - 2.f * wc + p1.z;
            if (s) wc = fminf(fmaxf(wc + STEPSZ * (ALPHA * d2w + fw), 0.f), DMAX);
            sm.s.buf[nxt][i].z = wc;
            fy = nfy; fx = nfx; fw = nfw;
            cur = nxt;
            barrier_lds_only();
        }
        float wm1 = sm.s.buf[cur][im1].z, wp1 = sm.s.buf[cur][ip1].z;
        float d2w = wm1 - 2.f * wc + wp1;
        wc = fminf(fmaxf(wc + STEPSZ * (ALPHA * d2w + fw), 0.f), DMAX);
        nodes[(size_t)b * NN + i] = make_float4(pc.x, pc.y, wc, 0.f);
        publish(&gates[1]);
    }

    // ---------------- Stage C: render (all blocks; 4 tiles each) -----------
    waitgate<16>(&gates[1], NB);
    int t = x;
    int wid = t >> 6;
    float bsum = 0.f;
    for (int k = 0; k < 4; ++k) {
        int tid = g * 4 + k;            // block's 4 tiles share one batch
        int b = tid >> 8;
        int tile = tid & 255;
        int tx0 = (tile & 7) << 5;      // 32 px wide
        int ty0 = (tile >> 3) << 3;     // 8 px tall
        int lx = t & 31, ly = t >> 5;

        float4 nv = nodes[(size_t)b * NN + t];
        float ddx = fmaxf(fabsf(nv.y - ((float)tx0 + 15.5f)) - 15.5f, 0.f);
        float ddy = fmaxf(fabsf(nv.x - ((float)ty0 + 3.5f)) - 3.5f, 0.f);
        float rad = DMAX + nv.z;
        bool cand = (ddx * ddx + ddy * ddy) < rad * rad;
        unsigned long long mask = __ballot(cand);
        if ((t & 63) == 0) wbase[wid] = __popcll(mask);
        __syncthreads();
        if (t == 0) {
            int s = 0;
#pragma unroll
            for (int wv = 0; wv < 4; ++wv) {
                int c = wbase[wv]; wbase[wv] = s; s += c;
            }
            total = s;
        }
        __syncthreads();
        if (cand) {
            int pos = wbase[wid] + __popcll(mask & ((1ULL << (t & 63)) - 1ULL));
            sm.r.list[pos] = nv;
        }
        __syncthreads();

        float fyc = (float)(ty0 + ly), fxc = (float)(tx0 + lx);
        float v = DMAX;
        int tot = total;
        for (int j = 0; j < tot; ++j) {
            float4 p = sm.r.list[j];
            float dy = fyc - p.x;
            float dx = fxc - p.y;
            float r2 = dy * dy + dx * dx;
            float tt = v + p.z;
            if (tt > 0.f && r2 < tt * tt)
                v = sqrtf(r2) - p.z;
        }
        float dm = fmaxf(v, 0.f);
        float diff = pd[((size_t)b * HH + ty0 + ly) * WW + tx0 + lx] - dm;
        float val = diff * diff;
        for (int off = 32; off > 0; off >>= 1) val += __shfl_down(val, off, 64);
        if ((t & 63) == 0) wsum[wid] = val;
        __syncthreads();
        if (t == 0) bsum += wsum[0] + wsum[1] + wsum[2] + wsum[3];
        __syncthreads();                 // list/wsum reuse next tile
    }
    if (t == 0) {
        __hip_atomic_store(&partial[g], bsum, __ATOMIC_RELEASE,
                           __HIP_MEMORY_SCOPE_AGENT);
        unsigned c = __hip_atomic_fetch_add(&gates[2], 1u, __ATOMIC_ACQ_REL,
                                            __HIP_MEMORY_SCOPE_AGENT);
        lastflag = (c == 255u);
    }
    __syncthreads();
    if (lastflag) {
        float v2 = __hip_atomic_load(&partial[t], __ATOMIC_ACQUIRE,
                                     __HIP_MEMORY_SCOPE_AGENT);
        for (int off = 32; off > 0; off >>= 1) v2 += __shfl_down(v2, off, 64);
        if ((t & 63) == 0) wsum[wid] = v2;
        __syncthreads();
        if (t == 0)
            out[0] = (wsum[0] + wsum[1] + wsum[2] + wsum[3]) *
                     (1.f / (float)(NB * HH * WW));
    }
}

extern "C" void kernel_launch(void* const* d_in, const int* in_sizes, int n_in,
                              void* d_out, int out_size, void* d_ws, size_t ws_size,
                              hipStream_t stream) {
    const float* pd       = (const float*)d_in[0];   // (B,1,H,W)
    const float* node_pos = (const float*)d_in[1];   // (B,N,2)
    const float* widths   = (const float*)d_in[2];   // (B,N)
    float* out = (float*)d_out;

    char* ws = (char*)d_ws;
    size_t rec_bytes = (size_t)NB * HH * WW * 32;    // 8 MB of records
    uint4*    rec     = (uint4*)ws;
    float4*   nodes   = (float4*)(ws + rec_bytes);
    float*    partial = (float*)(ws + rec_bytes + (size_t)NB * NN * sizeof(float4));
    unsigned* gates   = (unsigned*)(partial + 256);

    Flt flt;
    {
        float g[13];
        float s = 0.f;
        for (int i = 0; i < 13; ++i) {
            float xx = (float)(i - 6);
            g[i] = expf(-xx * xx / 8.f);
            s += g[i];
        }
        for (int i = 0; i < 13; ++i) {
            flt.g[i]  = g[i] / s;
            flt.dg[i] = -(float)(i - 6) / 4.f * flt.g[i];
        }
    }

    (void)hipMemsetAsync(gates, 0, 4 * sizeof(unsigned), stream);
    fused_kernel<<<256, 256, 0, stream>>>(pd, node_pos, widths, rec, nodes,
                                          partial, gates, out, flt);
}

// Round 10
// 126.557 us; speedup vs baseline: 2.3007x; 2.3007x over previous
//
#include <hip/hip_runtime.h>
#include <hip/hip_fp16.h>
#include <math.h>

#define HH 256
#define WW 256
#define NB 4
#define NN 256
#define NSTEPS 50
#define STEPSZ 0.1f
#define ALPHA 0.01f
#define BETA 0.005f
#define DMAX 15.0f
#define CTILE 4
#define CH (CTILE + 1 + 12)   // 17 staged rows: need CTILE+1 vertical results

struct Flt { float g[13]; float dg[13]; };

// Fused separable conv producing PRE-GATHERED bilinear records:
// per pixel (y,x) a 32B-aligned record with the 4 corner values
// (fy,fx,fw) at (y,x),(y,x+1),(y+1,x),(y+1,x+1) as 12 halfs (24B + pad).
// One snake sample then reads ONE cache line.
__global__ void conv_fused_kernel(const float* __restrict__ pd,
                                  uint4* __restrict__ rec, Flt flt) {
    int blk = blockIdx.x;           // b*64 + tile
    int b = blk >> 6;
    int t = blk & 63;
    int y0 = t * CTILE;
    int x = threadIdx.x;
    __shared__ float srow[CH][WW + 16];
    __shared__ float vres[CTILE + 1][WW + 2][3];
    for (int r = 0; r < CH; ++r) {
        int yy = y0 - 6 + r;
        float v = (yy >= 0 && yy < HH) ? pd[((size_t)b * HH + yy) * WW + x] : 0.f;
        srow[r][6 + x] = v;
        if (x < 6) { srow[r][x] = 0.f; srow[r][WW + 6 + x] = 0.f; }
    }
    __syncthreads();
    float4 h[CH];
#pragma unroll
    for (int r = 0; r < CH; ++r) {
        float sg = 0.f, sdg = 0.f, sga = 0.f, sdga = 0.f;
#pragma unroll
        for (int j = 0; j < 13; ++j) {
            float v = srow[r][x + j];
            float a = fabsf(v);
            sg   += flt.g[j]  * v;
            sdg  += flt.dg[j] * v;
            sga  += flt.g[j]  * a;
            sdga += flt.dg[j] * a;
        }
        h[r] = make_float4(sg, sdg, sga, sdga);
    }
#pragma unroll
    for (int rr = 0; rr <= CTILE; ++rr) {
        float g0 = 0.f, g1 = 0.f, w0 = 0.f, w1 = 0.f;
#pragma unroll
        for (int i2 = 0; i2 < 13; ++i2) {
            float4 v = h[rr + i2];
            g0 += flt.dg[i2] * v.x;   // fy: dg over y of (g over x)
            g1 += flt.g[i2]  * v.y;   // fx: g over y of (dg over x)
            w0 += flt.dg[i2] * v.z;
            w1 += flt.g[i2]  * v.w;
        }
        vres[rr][x][0] = 10.f * g0;
        vres[rr][x][1] = 10.f * g1;
        vres[rr][x][2] = 10.f * (w0 + w1);   // width force pre-summed (linear)
    }
    __syncthreads();
#pragma unroll
    for (int rr = 0; rr < CTILE; ++rr) {
        const float* c00 = vres[rr][x];
        const float* c01 = vres[rr][x + 1];       // x=255 reads garbage col; that
        const float* c10 = vres[rr + 1][x];       // record is never sampled
        const float* c11 = vres[rr + 1][x + 1];
        union { uint4 u; __half hh[8]; } lo;
        union { uint2 u; __half hh[4]; } hi;
        lo.hh[0] = __float2half(c00[0]); lo.hh[1] = __float2half(c00[1]);
        lo.hh[2] = __float2half(c00[2]);
        lo.hh[3] = __float2half(c01[0]); lo.hh[4] = __float2half(c01[1]);
        lo.hh[5] = __float2half(c01[2]);
        lo.hh[6] = __float2half(c10[0]); lo.hh[7] = __float2half(c10[1]);
        hi.hh[0] = __float2half(c10[2]);
        hi.hh[1] = __float2half(c11[0]); hi.hh[2] = __float2half(c11[1]);
        hi.hh[3] = __float2half(c11[2]);
        size_t ridx = ((size_t)b * HH + y0 + rr) * WW + x;
        rec[ridx * 2] = lo.u;
        *((uint2*)(rec + ridx * 2 + 1)) = hi.u;
    }
}

// One-cache-line bilinear sample from the pre-gathered record image.
__device__ __forceinline__ void sampleR(const uint4* __restrict__ rec,
                                        float py_, float px_,
                                        float& fy, float& fx, float& fw) {
    float yc = fminf(fmaxf(py_, 0.f), 254.999f);
    float xc = fminf(fmaxf(px_, 0.f), 254.999f);
    int y0 = (int)yc, x0 = (int)xc;
    float ty = yc - (float)y0, tx = xc - (float)x0;
    const uint4* p = rec + (size_t)((y0 << 8) + x0) * 2;
    union { uint4 u; __half h[8]; } lo;
    union { uint2 u; __half h[4]; } hi;
    lo.u = p[0];
    hi.u = *(const uint2*)(p + 1);
    float w00 = (1.f - ty) * (1.f - tx), w01 = (1.f - ty) * tx;
    float w10 = ty * (1.f - tx),         w11 = ty * tx;
    fy = __half2float(lo.h[0]) * w00 + __half2float(lo.h[3]) * w01 +
         __half2float(lo.h[6]) * w10 + __half2float(hi.h[1]) * w11;
    fx = __half2float(lo.h[1]) * w00 + __half2float(lo.h[4]) * w01 +
         __half2float(lo.h[7]) * w10 + __half2float(hi.h[2]) * w11;
    fw = __half2float(lo.h[2]) * w00 + __half2float(lo.h[5]) * w01 +
         __half2float(hi.h[0]) * w10 + __half2float(hi.h[3]) * w11;
}

// One block (4 waves) per batch, one node per thread. One gather + one
// barrier per step; gather result consumed only AFTER the next barrier.
// State packed float4 -> 4x ds_read_b128/step; position update + gather
// issue happen before the w-update ALU.
__global__ void snake_kernel(const uint4* __restrict__ rec,
                             const float* __restrict__ node_pos,
                             const float* __restrict__ widths,
                             float4* __restrict__ nodes_out,
                             unsigned* __restrict__ cnt) {
    int b = blockIdx.x;
    int i = threadIdx.x;
    if (b == 0 && i == 0) *cnt = 0;   // zero render's done-counter
    __shared__ float4 buf[2][NN];
    const uint4* img = rec + (size_t)b * HH * WW * 2;
    const float2* np2 = (const float2*)(node_pos + (size_t)b * NN * 2);
    float2 pc = np2[i];
    float wc = widths[(size_t)b * NN + i];
    buf[0][i] = make_float4(pc.x, pc.y, wc, 0.f);
    int im1 = (i > 0) ? i - 1 : 0;
    int im2 = (i > 1) ? i - 2 : 0;
    int ip1 = (i < NN - 1) ? i + 1 : NN - 1;
    int ip2 = (i < NN - 2) ? i + 2 : NN - 1;
    float fy, fx, fw;
    sampleR(img, pc.x, pc.y, fy, fx, fw);   // force at p_0 (fw unused at s=0)
    __syncthreads();
    int cur = 0;
    for (int s = 0; s < NSTEPS; ++s) {
        int nxt = cur ^ 1;
        float4 m2 = buf[cur][im2], m1 = buf[cur][im1];
        float4 p1 = buf[cur][ip1], p2 = buf[cur][ip2];
        float d2y = m1.x - 2.f * pc.x + p1.x;
        float d2x = m1.y - 2.f * pc.y + p1.y;
        float d2my = m2.x - 2.f * m1.x + pc.x;
        float d2mx = m2.y - 2.f * m1.y + pc.y;
        float d2py = pc.x - 2.f * p1.x + p2.x;
        float d2px = pc.y - 2.f * p1.y + p2.y;
        if (i == 0)      { d2my = d2y; d2mx = d2x; }
        if (i == NN - 1) { d2py = d2y; d2px = d2x; }
        float d4y = d2my - 2.f * d2y + d2py;
        float d4x = d2mx - 2.f * d2x + d2px;
        pc.x = fminf(fmaxf(pc.x + STEPSZ * (ALPHA * d2y - BETA * d4y + fy), 0.f),
                     (float)(HH - 1));
        pc.y = fminf(fmaxf(pc.y + STEPSZ * (ALPHA * d2x - BETA * d4x + fx), 0.f),
                     (float)(WW - 1));
        *((float2*)&buf[nxt][i]) = pc;          // position visible next step
        float nfy, nfx, nfw;
        sampleR(img, pc.x, pc.y, nfy, nfx, nfw);  // issued early; used next iter
        // w_s = w_{s-1} + dt*(ALPHA*d2(w_{s-1}) + fw@p_s)   [skip at s=0]
        float d2w = m1.z - 2.f * wc + p1.z;
        if (s) wc = fminf(fmaxf(wc + STEPSZ * (ALPHA * d2w + fw), 0.f), DMAX);
        buf[nxt][i].z = wc;
        fy = nfy; fx = nfx; fw = nfw;
        cur = nxt;
        __syncthreads();
    }
    // final pending w update with fw@p_NSTEPS
    float wm1 = buf[cur][im1].z, wp1 = buf[cur][ip1].z;
    float d2w = wm1 - 2.f * wc + wp1;
    wc = fminf(fmaxf(wc + STEPSZ * (ALPHA * d2w + fw), 0.f), DMAX);
    nodes_out[(size_t)b * NN + i] = make_float4(pc.x, pc.y, wc, 0.f);
}

// One block = 32x8 px tile. Cull nodes (rect distance < DMAX+w), compact to
// LDS, scan with running-threshold test (sqrt only on improvement). Last
// finishing block reduces all partials.
__global__ void render_loss_kernel(const float* __restrict__ pd,
                                   const float4* __restrict__ nodes,
                                   float* __restrict__ partial,
                                   unsigned* __restrict__ cnt,
                                   float* __restrict__ out) {
    int blk = blockIdx.x;
    int b = blk >> 8;                 // 256 tiles per batch
    int tile = blk & 255;
    int tx0 = (tile & 7) << 5;        // 32 px wide
    int ty0 = (tile >> 3) << 3;       // 8 px tall
    int t = threadIdx.x;
    int lx = t & 31, ly = t >> 5;
    __shared__ float4 list[NN];
    __shared__ int wbase[4];
    __shared__ int total;
    __shared__ float wsum[4];
    __shared__ int lastflag;

    float4 nv = nodes[(size_t)b * NN + t];
    float ddx = fmaxf(fabsf(nv.y - ((float)tx0 + 15.5f)) - 15.5f, 0.f);
    float ddy = fmaxf(fabsf(nv.x - ((float)ty0 + 3.5f)) - 3.5f, 0.f);
    float rad = DMAX + nv.z;
    bool cand = (ddx * ddx + ddy * ddy) < rad * rad;
    unsigned long long mask = __ballot(cand);
    int wid = t >> 6;
    if ((t & 63) == 0) wbase[wid] = __popcll(mask);
    __syncthreads();
    if (t == 0) {
        int s = 0;
#pragma unroll
        for (int wv = 0; wv < 4; ++wv) { int c = wbase[wv]; wbase[wv] = s; s += c; }
        total = s;
    }
    __syncthreads();
    if (cand) {
        int pos = wbase[wid] + __popcll(mask & ((1ULL << (t & 63)) - 1ULL));
        list[pos] = nv;
    }
    __syncthreads();

    float fyc = (float)(ty0 + ly), fxc = (float)(tx0 + lx);
    float v = DMAX;
    int tot = total;
    for (int j = 0; j < tot; ++j) {
        float4 p = list[j];
        float dy = fyc - p.x;
        float dx = fxc - p.y;
        float r2 = dy * dy + dx * dx;
        float tt = v + p.z;
        if (tt > 0.f && r2 < tt * tt)
            v = sqrtf(r2) - p.z;
    }
    float dm = fmaxf(v, 0.f);
    float diff = pd[((size_t)b * HH + ty0 + ly) * WW + tx0 + lx] - dm;
    float val = diff * diff;
    for (int off = 32; off > 0; off >>= 1) val += __shfl_down(val, off, 64);
    if ((t & 63) == 0) wsum[wid] = val;
    __syncthreads();
    if (t == 0) {
        float s = wsum[0] + wsum[1] + wsum[2] + wsum[3];
        __hip_atomic_store(&partial[blk], s, __ATOMIC_RELEASE,
                           __HIP_MEMORY_SCOPE_AGENT);
        unsigned c = __hip_atomic_fetch_add(cnt, 1u, __ATOMIC_ACQ_REL,
                                            __HIP_MEMORY_SCOPE_AGENT);
        lastflag = (c == (unsigned)(NB * 256 - 1));
    }
    __syncthreads();
    if (lastflag) {
        float v2 = 0.f;
        for (int j = t; j < NB * 256; j += 256)
            v2 += __hip_atomic_load(&partial[j], __ATOMIC_ACQUIRE,
                                    __HIP_MEMORY_SCOPE_AGENT);
        for (int off = 32; off > 0; off >>= 1) v2 += __shfl_down(v2, off, 64);
        if ((t & 63) == 0) wsum[wid] = v2;
        __syncthreads();
        if (t == 0)
            out[0] = (wsum[0] + wsum[1] + wsum[2] + wsum[3]) *
                     (1.f / (float)(NB * HH * WW));
    }
}

extern "C" void kernel_launch(void* const* d_in, const int* in_sizes, int n_in,
                              void* d_out, int out_size, void* d_ws, size_t ws_size,
                              hipStream_t stream) {
    const float* pd       = (const float*)d_in[0];   // (B,1,H,W)
    const float* node_pos = (const float*)d_in[1];   // (B,N,2)
    const float* widths   = (const float*)d_in[2];   // (B,N)
    float* out = (float*)d_out;

    char* ws = (char*)d_ws;
    size_t rec_bytes = (size_t)NB * HH * WW * 32;    // 8 MB of records
    uint4*    rec     = (uint4*)ws;
    float4*   nodes   = (float4*)(ws + rec_bytes);
    float*    partial = (float*)(ws + rec_bytes + (size_t)NB * NN * sizeof(float4));
    unsigned* cnt     = (unsigned*)(partial + NB * 256);

    Flt flt;
    {
        float g[13];
        float s = 0.f;
        for (int i = 0; i < 13; ++i) {
            float xx = (float)(i - 6);
            g[i] = expf(-xx * xx / 8.f);
            s += g[i];
        }
        for (int i = 0; i < 13; ++i) {
            flt.g[i]  = g[i] / s;
            flt.dg[i] = -(float)(i - 6) / 4.f * flt.g[i];
        }
    }

    conv_fused_kernel<<<NB * 64, 256, 0, stream>>>(pd, rec, flt);
    snake_kernel<<<NB, NN, 0, stream>>>(rec, node_pos, widths, nodes, cnt);
    render_loss_kernel<<<NB * 256, 256, 0, stream>>>(pd, nodes, partial, cnt, out);
}